// Round 2
// baseline (151.766 us; speedup 1.0000x reference)
//
#include <hip/hip_runtime.h>

// Problem constants: B=4, N=1024, D=256, H=8
// q/k/v stored bf16 in qkvb[seg][tok][h*256+d]  (tok-major, stride 2048),
// tok = b*1024+n.  Wqkv pre-transposed + column-permuted: whT row
// p = seg*2048+h*256+d holds original column seg*2048+d*8+h.  W0
// pre-transposed with the same k-permutation: w0T[e][h*256+d] = W0[d*8+h][e].
// Softmax: NO max subtraction (|s| <~ 0.6, exp safe); q pre-scaled by D^-0.5.
// R9: diag row-scaling commutes through W0 within a head -> y_h = v_h @ W0_h
// is scores-independent; dg applied in reduce_out (f32).
// R10: both MFMA kernels ported to the 256x256 / BK=64 / 8-wave / 8-phase
// counted-vmcnt template (m201): st_16x32 LDS swizzle done via inverse-
// swizzled GLOBAL source (LDS dest linear, rule #21), phases never drain
// vmcnt to 0 mid-loop, setprio(1) around each 16-MFMA cluster.
// Stage schedule (derived, race-free): half-tile staged in phase p was last
// read in phase <= p-1; vmcnt(4) checkpoints at phases 4 and 8 (vmcnt(0) in
// final iteration only).

#define SEGSZ 8388608  // elements per q/k/v segment = 4096 tok * 2048

typedef short v8s __attribute__((ext_vector_type(8)));
typedef float v4f __attribute__((ext_vector_type(4)));

__device__ __forceinline__ ushort f2bf(float v) {
  union { float f; unsigned u; } x; x.f = v;
  const unsigned r = x.u + 0x7fff + ((x.u >> 16) & 1);   // RTNE
  return (ushort)(r >> 16);
}
__device__ __forceinline__ float bf2f(ushort v) {
  union { unsigned u; float f; } x; x.u = ((unsigned)v) << 16;
  return x.f;
}

#define GLOAD_LDS16(g, l)                                            \
  __builtin_amdgcn_global_load_lds(                                  \
      (const __attribute__((address_space(1))) void*)(g),            \
      (__attribute__((address_space(3))) void*)(l), 16, 0, 0)

#define SBAR()   asm volatile("s_barrier" ::: "memory")
#define VMCNT4() asm volatile("s_waitcnt vmcnt(4)" ::: "memory")
#define VMCNT0() asm volatile("s_waitcnt vmcnt(0)" ::: "memory")

// ---------------------------------------------------------------------------
// prep: fused conversions.  blocks 0..1023: x->xb (bf16).
// blocks 1024..1407: Wqkv transpose+permute -> whT.
// blocks 1408..1535: W0 transpose+permute -> w0T.  grid (1536), 256 thr.
// ---------------------------------------------------------------------------
__global__ __launch_bounds__(256) void prep(
    const float* __restrict__ X, const float* __restrict__ Wqkv,
    const float* __restrict__ W0, ushort* __restrict__ xb,
    ushort* __restrict__ whT, ushort* __restrict__ w0T) {
  __shared__ float T[64][65];
  const int tid = threadIdx.x;
  int bid = blockIdx.x;

  if (bid < 1024) {  // ---- x -> bf16 ----
    const size_t i = ((size_t)bid * 256 + tid) * 4;
    const float4 v = *(const float4*)&X[i];
    ushort4 hv = {f2bf(v.x), f2bf(v.y), f2bf(v.z), f2bf(v.w)};
    *(ushort4*)&xb[i] = hv;
    return;
  }
  bid -= 1024;
  if (bid < 384) {  // ---- Wqkv [256][6144] -> whT [6144][256], permuted ----
    const int n0 = (bid % 96) * 64;
    const int k0 = (bid / 96) * 64;
    {
      const int row = tid >> 2;
      const int c0 = (tid & 3) * 16;
#pragma unroll
      for (int j = 0; j < 16; j += 4) {
        const float4 v = *(const float4*)&Wqkv[(size_t)(k0 + row) * 6144 + n0 + c0 + j];
        T[row][c0 + j + 0] = v.x; T[row][c0 + j + 1] = v.y;
        T[row][c0 + j + 2] = v.z; T[row][c0 + j + 3] = v.w;
      }
    }
    __syncthreads();
    {
      const int nn = tid >> 2;
      const int kk0 = (tid & 3) * 16;
      const int n = n0 + nn;
      const int seg = n >> 11, h = n & 7, d = (n & 2047) >> 3;
      const int p = seg * 2048 + h * 256 + d;
      ushort hv[16];
#pragma unroll
      for (int j = 0; j < 16; ++j) hv[j] = f2bf(T[kk0 + j][nn]);
      const size_t base = (size_t)p * 256 + k0 + kk0;
#pragma unroll
      for (int j = 0; j < 16; j += 8) *(v8s*)&whT[base + j] = *(v8s*)&hv[j];
    }
    return;
  }
  bid -= 384;
  {  // ---- W0 [2048][256] -> w0T [256][2048], k-permuted ----
    const int e0 = (bid & 3) * 64;
    const int k0 = (bid >> 2) * 64;
    {
      const int row = tid >> 2;
      const int c0 = (tid & 3) * 16;
#pragma unroll
      for (int j = 0; j < 16; j += 4) {
        const float4 v = *(const float4*)&W0[(size_t)(k0 + row) * 256 + e0 + c0 + j];
        T[row][c0 + j + 0] = v.x; T[row][c0 + j + 1] = v.y;
        T[row][c0 + j + 2] = v.z; T[row][c0 + j + 3] = v.w;
      }
    }
    __syncthreads();
    {
      const int ee = tid >> 2;
      const int kk0 = (tid & 3) * 16;
#pragma unroll
      for (int j = 0; j < 16; ++j) {
        const int k = k0 + kk0 + j;      // original row = d*8+h
        const int d = k >> 3, h = k & 7;
        w0T[(size_t)(e0 + ee) * 2048 + h * 256 + d] = f2bf(T[kk0 + j][ee]);
      }
    }
  }
}

// ---------------------------------------------------------------------------
// 256x256 tile, BK=64, 8 waves (512 thr), 8-phase pipelined GEMM body.
// K = 256 fixed (4 K-tiles, 2 iterations).  acc[qr][qc][ri][ci] fragments:
// C row = qr*128 + wm*64 + ri*16 + quad*4 + rg, col = qc*128 + wn*32 +
// ci*16 + l15.  LDS A/B: [2 buf][256][64] bf16, st_16x32 swizzle (col bit4
// ^= row bit2) applied via inverse-swizzled global source on stage and the
// same XOR on ds_read.
// ---------------------------------------------------------------------------
template <int STRIDE>
__device__ __forceinline__ void gemm256_8ph(
    const ushort* __restrict__ gA, const ushort* __restrict__ gB,
    ushort (&AS)[2][16384], ushort (&BS)[2][16384],
    v4f (&acc)[2][2][4][2]) {
  const int tid = threadIdx.x;
  const int wave = tid >> 6, lane = tid & 63;
  const int wm = wave >> 2, wn = wave & 3;
  const int quad = lane >> 4, l15 = lane & 15;
  // stage-side lane mapping (LDS dest linear; global source inverse-swizzled)
  const int srow = wave * 8 + (lane >> 3);
  const int scol = ((lane & 7) << 3) ^ (((lane >> 5) & 1) << 4);
  // read-side swizzled column base
  const int cq = (quad * 8) ^ (((l15 >> 2) & 1) << 4);

  auto stage = [&](int op, int buf, int half, int kt) {
#pragma unroll
    for (int j = 0; j < 2; ++j) {
      const size_t grow =
          (size_t)(half * 128 + j * 64 + srow) * STRIDE + kt * 64 + scol;
      ushort* lb = op ? &BS[buf][half * 8192 + j * 4096 + wave * 512]
                      : &AS[buf][half * 8192 + j * 4096 + wave * 512];
      GLOAD_LDS16((op ? gB : gA) + grow, lb);
    }
  };

  // prologue: K0 all 4 half-tiles (8 loads), K1 A-half0 + B-half0 (4 loads)
  stage(0, 0, 0, 0); stage(0, 0, 1, 0); stage(1, 0, 0, 0); stage(1, 0, 1, 0);
  stage(0, 1, 0, 1); stage(1, 1, 0, 1);
  VMCNT4();   // K0 landed (K1's 4 loads may remain outstanding)
  SBAR();

  for (int it = 0; it < 2; ++it) {
    const int t0 = it * 2;
#pragma unroll
    for (int p = 0; p < 8; ++p) {
      const int kb = p >> 2;               // read buffer / relative K-tile
      const int qr = (p >> 1) & 1, qc = p & 1;
      v8s af[4][2], bfr[2][2];
#pragma unroll
      for (int ri = 0; ri < 4; ++ri) {
        const int r = qr * 128 + wm * 64 + ri * 16 + l15;
#pragma unroll
        for (int ks = 0; ks < 2; ++ks)
          af[ri][ks] = *(const v8s*)&AS[kb][r * 64 + ks * 32 + cq];
      }
#pragma unroll
      for (int ci = 0; ci < 2; ++ci) {
        const int r = qc * 128 + wn * 32 + ci * 16 + l15;
#pragma unroll
        for (int ks = 0; ks < 2; ++ks)
          bfr[ci][ks] = *(const v8s*)&BS[kb][r * 64 + ks * 32 + cq];
      }
      {  // stage schedule: ph1..8 -> A1/B1(t0+1), A0/B0(t0+2), A1/B1(t0+2),
         //                 A0/B0(t0+3); staged half was last read ph<=p-1.
        const int st = t0 + 1 + ((p + 2) >> 2);
        if (st < 4) stage(p & 1, st & 1, 1 - ((p >> 1) & 1), st);
      }
      SBAR();
      __builtin_amdgcn_s_setprio(1);
#pragma unroll
      for (int ri = 0; ri < 4; ++ri)
#pragma unroll
        for (int ci = 0; ci < 2; ++ci)
#pragma unroll
          for (int ks = 0; ks < 2; ++ks)
            acc[qr][qc][ri][ci] = __builtin_amdgcn_mfma_f32_16x16x32_bf16(
                af[ri][ks], bfr[ci][ks], acc[qr][qc][ri][ci], 0, 0, 0);
      __builtin_amdgcn_s_setprio(0);
      if (p == 3 || p == 7) { if (it == 0) VMCNT4(); else VMCNT0(); }
      SBAR();
    }
  }
}

// ---------------------------------------------------------------------------
// Kernel A: qkv = x @ Wqkv + bqkv.  grid (24, 16), 512 thr, 256x256 tile.
// ---------------------------------------------------------------------------
__global__ __launch_bounds__(512, 2) void qkv8(
    const ushort* __restrict__ xb, const ushort* __restrict__ whT,
    const float* __restrict__ bias, ushort* __restrict__ qkvb) {
  __shared__ ushort AS[2][16384];
  __shared__ ushort BS[2][16384];
  const int tid = threadIdx.x;
  const int wave = tid >> 6, lane = tid & 63;
  const int wm = wave >> 2, wn = wave & 3;
  const int quad = lane >> 4, l15 = lane & 15;
  const int c0 = blockIdx.x * 256;
  const int r0 = blockIdx.y * 256;

  v4f acc[2][2][4][2] = {};
  gemm256_8ph<256>(xb + (size_t)r0 * 256, whT + (size_t)c0 * 256, AS, BS, acc);

#pragma unroll
  for (int qc2 = 0; qc2 < 2; ++qc2)
#pragma unroll
    for (int ci = 0; ci < 2; ++ci) {
      const int cc = c0 + qc2 * 128 + wn * 32 + ci * 16 + l15;
      const int cseg = cc >> 11;
      const int hh = (cc & 2047) >> 8;
      const int d = cc & 255;
      const float bv = bias[cseg * 2048 + d * 8 + hh];
#pragma unroll
      for (int qr = 0; qr < 2; ++qr)
#pragma unroll
        for (int ri = 0; ri < 4; ++ri)
#pragma unroll
          for (int rg = 0; rg < 4; ++rg) {
            const int r = r0 + qr * 128 + wm * 64 + ri * 16 + quad * 4 + rg;
            const int g = r * 3 + cseg;
            const int seg = g >> 12;       // q/k/v
            const int tok = g & 4095;      // = b*1024 + n
            float val = acc[qr][qc2][ri][ci][rg] + bv;
            if (seg == 0) val *= 0.0625f;  // pre-scale q by D^-0.5
            qkvb[(size_t)seg * SEGSZ + (size_t)tok * 2048 + hh * 256 + d] = f2bf(val);
          }
    }
}

// ---------------------------------------------------------------------------
// Kernel B (fused): blocks 0..511 = score stats (256x256 tiles, col-sums of
// exp + diagonal); blocks 512..639 = y_h = v_h @ W0_h partials (no dg).
// Scores ids keep id%8 == bh%8 (XCD L2 swizzle); y blocks fill the tail.
// ---------------------------------------------------------------------------
__global__ __launch_bounds__(512, 2) void mid8(
    const ushort* __restrict__ qkvb, const ushort* __restrict__ w0T,
    float* __restrict__ pl, float* __restrict__ sd_ws,
    ushort* __restrict__ partial) {
  __shared__ ushort AS[2][16384];
  __shared__ ushort BS[2][16384];
  __shared__ float redL[2][4][64];
  const int tid = threadIdx.x;
  const int wave = tid >> 6, lane = tid & 63;
  const int wm = wave >> 2, wn = wave & 3;
  const int quad = lane >> 4, l15 = lane & 15;
  const int id = blockIdx.x;

  v4f acc[2][2][4][2] = {};

  if (id < 512) {
    // ---------------- scores branch ----------------
    const int c = id & 7, inner = id >> 3;
    const int bh = (inner >> 4) * 8 + c;
    const int tile = inner & 15;
    const int tt0 = (tile >> 2) * 256;     // key-column tile
    const int nn0 = (tile & 3) * 256;      // query-row tile (inner: L2 reuse)
    const int b = bh >> 3, h = bh & 7;
    const ushort* Qg = qkvb + (size_t)b * 2097152 + h * 256 + (size_t)nn0 * 2048;
    const ushort* Kg = qkvb + SEGSZ + (size_t)b * 2097152 + h * 256 + (size_t)tt0 * 2048;
    gemm256_8ph<2048>(Qg, Kg, AS, BS, acc);

    // ---- column sums of exp(s): C col = key t, rows = queries n ----
    float lsum[2][2];
#pragma unroll
    for (int qc2 = 0; qc2 < 2; ++qc2)
#pragma unroll
      for (int ci = 0; ci < 2; ++ci) {
        float s = 0.f;
#pragma unroll
        for (int qr = 0; qr < 2; ++qr)
#pragma unroll
          for (int ri = 0; ri < 4; ++ri)
#pragma unroll
            for (int rg = 0; rg < 4; ++rg)
              s += __expf(acc[qr][qc2][ri][ci][rg]);
        s += __shfl_xor(s, 16, 64);
        s += __shfl_xor(s, 32, 64);
        lsum[qc2][ci] = s;                 // sum over this wave's 128 rows
      }
    if (quad == 0) {
#pragma unroll
      for (int qc2 = 0; qc2 < 2; ++qc2)
#pragma unroll
        for (int ci = 0; ci < 2; ++ci)
          redL[wm][wn][(qc2 * 2 + ci) * 16 + l15] = lsum[qc2][ci];
    }
    __syncthreads();
    if (wm == 0 && quad == 0) {
#pragma unroll
      for (int qc2 = 0; qc2 < 2; ++qc2)
#pragma unroll
        for (int ci = 0; ci < 2; ++ci) {
          const int t = tt0 + qc2 * 128 + wn * 32 + ci * 16 + l15;
          const float l = lsum[qc2][ci] + redL[1][wn][(qc2 * 2 + ci) * 16 + l15];
          pl[((size_t)bh * 1024 + t) * 4 + (nn0 >> 8)] = l;
        }
    }

    // ---- diagonal capture (tt0 == nn0 tiles) ----
    if (tt0 == nn0) {
#pragma unroll
      for (int qr = 0; qr < 2; ++qr)
#pragma unroll
        for (int ci = 0; ci < 2; ++ci)
#pragma unroll
          for (int ri = 0; ri < 4; ++ri)
#pragma unroll
            for (int rg = 0; rg < 4; ++rg)
              if (wn * 2 + ci - wm * 4 == ri && (l15 >> 2) == quad &&
                  (l15 & 3) == rg) {
                const int t = tt0 + qr * 128 + wm * 64 + ri * 16 + l15;
                sd_ws[(size_t)bh * 1024 + t] = acc[qr][qr][ri][ci][rg];
              }
    }
  } else {
    // ---------------- y = v_h @ W0_h branch (no dg) ----------------
    const int j = id - 512;
    const int h = j >> 4;
    const int tok0 = (j & 15) * 256;
    const ushort* Ag = qkvb + 2 * (size_t)SEGSZ + (size_t)tok0 * 2048 + h * 256;
    const ushort* Bg = w0T + h * 256;      // rows e = 0..255, stride 2048
    gemm256_8ph<2048>(Ag, Bg, AS, BS, acc);

#pragma unroll
    for (int qr = 0; qr < 2; ++qr)
#pragma unroll
      for (int ri = 0; ri < 4; ++ri)
#pragma unroll
        for (int rg = 0; rg < 4; ++rg) {
          const int tok = tok0 + qr * 128 + wm * 64 + ri * 16 + quad * 4 + rg;
#pragma unroll
          for (int qc2 = 0; qc2 < 2; ++qc2)
#pragma unroll
            for (int ci = 0; ci < 2; ++ci) {
              const int e = qc2 * 128 + wn * 32 + ci * 16 + l15;
              partial[(size_t)h * 1048576 + (size_t)tok * 256 + e] =
                  f2bf(acc[qr][qc2][ri][ci][rg]);
            }
        }
  }
}

// ---------------------------------------------------------------------------
// Fallback kernels (workspace too small for partials): atomic av with
// in-kernel diag (128x128 legacy tile).  Not used on the benched path.
// ---------------------------------------------------------------------------
__global__ __launch_bounds__(256) void av_atomic(
    const ushort* __restrict__ vb, const ushort* __restrict__ w0T,
    const float* __restrict__ pl, const float* __restrict__ sd,
    float* __restrict__ out) {
  __shared__ ushort As[128 * 32];
  __shared__ ushort Bs[128 * 32];
  __shared__ float diagS[128];
  const int tid = threadIdx.x;
  const int wave = tid >> 6, lane = tid & 63;
  const int quad = lane >> 4, l15 = lane & 15;
  const int e0 = blockIdx.x * 128;
  const int tok0 = blockIdx.y * 128;
  const int h = blockIdx.z;
  const int kbase = h * 256;
  const int wr = (wave >> 1) * 64;
  const int wc = (wave & 1) * 64;

  if (tid < 128) {
    const int bh = (tok0 >> 10) * 8 + h;
    const int t = (tok0 & 1023) + tid;
    const size_t base = ((size_t)bh * 1024 + t) * 4;
    float l = 0.f;
#pragma unroll
    for (int cc = 0; cc < 4; ++cc) l += pl[base + cc];
    diagS[tid] = __expf(sd[(size_t)bh * 1024 + t]) / l;
  }

  v4f acc[4][4] = {};

  for (int d0 = 0; d0 < 256; d0 += 32) {
#pragma unroll
    for (int half = 0; half < 2; ++half) {
      const int rr = wave * 32 + half * 16;
      const int row = rr + (lane >> 2);
      const int gcol = kbase + d0 + (lane & 3) * 8;
      GLOAD_LDS16(vb + (size_t)(tok0 + row) * 2048 + gcol, &As[rr * 32]);
      GLOAD_LDS16(w0T + (size_t)(e0 + row) * 2048 + gcol, &Bs[rr * 32]);
    }
    __syncthreads();

    v8s aF[4], bF[4];
#pragma unroll
    for (int i = 0; i < 4; ++i) {
      aF[i] = *(const v8s*)&As[(wr + i * 16 + l15) * 32 + quad * 8];
      bF[i] = *(const v8s*)&Bs[(wc + i * 16 + l15) * 32 + quad * 8];
    }
#pragma unroll
    for (int ri = 0; ri < 4; ++ri)
#pragma unroll
      for (int ci = 0; ci < 4; ++ci)
        acc[ri][ci] =
            __builtin_amdgcn_mfma_f32_16x16x32_bf16(aF[ri], bF[ci], acc[ri][ci], 0, 0, 0);
    __syncthreads();
  }

#pragma unroll
  for (int ri = 0; ri < 4; ++ri)
#pragma unroll
    for (int rg = 0; rg < 4; ++rg) {
      const int lrow = wr + ri * 16 + quad * 4 + rg;
      const int tok = tok0 + lrow;
      const float dg = diagS[lrow];
#pragma unroll
      for (int ci = 0; ci < 4; ++ci) {
        const int e = e0 + wc + ci * 16 + l15;
        atomicAdd(&out[(size_t)tok * 256 + e], acc[ri][ci][rg] * dg);
      }
    }
}

__global__ void init_out(const float* __restrict__ b0, float* __restrict__ out) {
  const int i = blockIdx.x * 256 + threadIdx.x;
  const int e0 = (i & 63) << 2;
  *(float4*)&out[(size_t)i * 4] = *(const float4*)&b0[e0];
}

// ---------------------------------------------------------------------------
// reduce_out: out[tok][e] = b0[e] + sum_h dg_h(tok) * y_h[tok][e].
// dg computed per-block in LDS: block covers 4 tokens (256 float4-groups).
// ---------------------------------------------------------------------------
__global__ void reduce_out(const ushort* __restrict__ partial,
                           const float* __restrict__ pl,
                           const float* __restrict__ sd,
                           const float* __restrict__ b0, float* __restrict__ out) {
  __shared__ float dgS[32];
  const int i = blockIdx.x * 256 + threadIdx.x;  // 262144 float4 groups
  const int tbase = blockIdx.x * 4;              // 4 tokens per block
  if (threadIdx.x < 32) {
    const int tl = threadIdx.x >> 3, h = threadIdx.x & 7;
    const int tok = tbase + tl;
    const int bh = (tok >> 10) * 8 + h;
    const int t = tok & 1023;
    const size_t base = ((size_t)bh * 1024 + t) * 4;
    float l = 0.f;
#pragma unroll
    for (int cc = 0; cc < 4; ++cc) l += pl[base + cc];
    dgS[threadIdx.x] = __expf(sd[(size_t)bh * 1024 + t]) / l;
  }
  __syncthreads();
  const int tl = threadIdx.x >> 6;
  const int e0 = (i & 63) << 2;
  float4 a = *(const float4*)&b0[e0];
#pragma unroll
  for (int h = 0; h < 8; ++h) {
    const float dg = dgS[tl * 8 + h];
    const ushort4 p = *(const ushort4*)&partial[(size_t)h * 1048576 + (size_t)i * 4];
    a.x += dg * bf2f(p.x); a.y += dg * bf2f(p.y);
    a.z += dg * bf2f(p.z); a.w += dg * bf2f(p.w);
  }
  *(float4*)&out[(size_t)i * 4] = a;
}

extern "C" void kernel_launch(void* const* d_in, const int* in_sizes, int n_in,
                              void* d_out, int out_size, void* d_ws, size_t ws_size,
                              hipStream_t stream) {
  const float* x    = (const float*)d_in[0];
  const float* Wqkv = (const float*)d_in[1];
  const float* bqkv = (const float*)d_in[2];
  const float* W0   = (const float*)d_in[3];
  const float* b0   = (const float*)d_in[4];
  float* out = (float*)d_out;

  float*  pl   = (float*)d_ws;                     // 262144 f (131072 used)
  float*  sd   = pl + 262144;                      // 32768 f
  ushort* qkvb = (ushort*)(sd + 32768);            // 3*SEGSZ us (q|k|v)
  ushort* xb   = qkvb + 3 * (size_t)SEGSZ;         // 1048576 us
  ushort* whT  = xb + 1048576;                     // 1572864 us
  ushort* w0T  = whT + 1572864;                    // 524288 us
  ushort* partial = w0T + 524288;                  // 8*1048576 us (optional)

  ushort* vb = qkvb + 2 * (size_t)SEGSZ;

  const size_t need_base =
      (size_t)(262144 + 32768) * 4 + (size_t)SEGSZ * 3 * 2 +
      (size_t)(1048576 + 1572864 + 524288) * 2;
  const bool full = ws_size >= need_base + (size_t)8 * 1048576 * 2;

  prep<<<1536, 256, 0, stream>>>(x, Wqkv, W0, xb, whT, w0T);
  qkv8<<<dim3(24, 16), 512, 0, stream>>>(xb, whT, bqkv, qkvb);
  if (full) {
    mid8<<<640, 512, 0, stream>>>(qkvb, w0T, pl, sd, partial);
    reduce_out<<<1024, 256, 0, stream>>>(partial, pl, sd, b0, out);
  } else {
    mid8<<<512, 512, 0, stream>>>(qkvb, w0T, pl, sd, nullptr);
    init_out<<<1024, 256, 0, stream>>>(b0, out);
    av_atomic<<<dim3(2, 32, 8), 256, 0, stream>>>(vb, w0T, pl, sd, out);
  }
}

// Round 3
// 142.249 us; speedup vs baseline: 1.0669x; 1.0669x over previous
//
#include <hip/hip_runtime.h>

// Problem constants: B=4, N=1024, D=256, H=8
// q/k/v stored bf16 in qkvb[seg][tok][h*256+d]  (tok-major, stride 2048),
// tok = b*1024+n.  Wqkv pre-transposed + column-permuted: whT row
// p = seg*2048+h*256+d holds original column seg*2048+d*8+h.  W0
// pre-transposed with the same k-permutation: w0T[e][h*256+d] = W0[d*8+h][e].
// Softmax: NO max subtraction (|s| <~ 0.6, exp safe); q pre-scaled by D^-0.5.
// R9: diag row-scaling commutes through W0 within a head -> y_h = v_h @ W0_h
// is scores-independent; dg applied in reduce_out (f32).
// R10: 256x256 / BK=64 / 8-wave / 8-phase counted-vmcnt template.
// R11 (post-mortem of R10): swizzle was WRONG (single-bit XOR left all lanes
// on banks {0,4,8,12}: 3.9M conflicts, MfmaUtil 13%).  Correct mapping:
// physical 16B-slot = logical_slot ^ (row&7)  (slot = col_ushort>>3, 8 slots
// per 128B row).  Applied as inverse-swizzled GLOBAL source on stage (LDS
// dest linear, rule #21) and the same XOR on ds_read.  Schedule itself is
// race-free and was verified correct in R10 (passed, absmax 7.6e-6).
// Stage schedule: half-tile staged in phase p was last read in phase <= p-1;
// vmcnt(4) checkpoints at phases 4 and 8 (vmcnt(0) in final iteration only).

#define SEGSZ 8388608  // elements per q/k/v segment = 4096 tok * 2048

typedef short v8s __attribute__((ext_vector_type(8)));
typedef float v4f __attribute__((ext_vector_type(4)));

__device__ __forceinline__ ushort f2bf(float v) {
  union { float f; unsigned u; } x; x.f = v;
  const unsigned r = x.u + 0x7fff + ((x.u >> 16) & 1);   // RTNE
  return (ushort)(r >> 16);
}
__device__ __forceinline__ float bf2f(ushort v) {
  union { unsigned u; float f; } x; x.u = ((unsigned)v) << 16;
  return x.f;
}

#define GLOAD_LDS16(g, l)                                            \
  __builtin_amdgcn_global_load_lds(                                  \
      (const __attribute__((address_space(1))) void*)(g),            \
      (__attribute__((address_space(3))) void*)(l), 16, 0, 0)

#define SBAR()   asm volatile("s_barrier" ::: "memory")
#define VMCNT4() asm volatile("s_waitcnt vmcnt(4)" ::: "memory")
#define VMCNT0() asm volatile("s_waitcnt vmcnt(0)" ::: "memory")

// ---------------------------------------------------------------------------
// prep: fused conversions.  blocks 0..1023: x->xb (bf16).
// blocks 1024..1407: Wqkv transpose+permute -> whT.
// blocks 1408..1535: W0 transpose+permute -> w0T.  grid (1536), 256 thr.
// ---------------------------------------------------------------------------
__global__ __launch_bounds__(256) void prep(
    const float* __restrict__ X, const float* __restrict__ Wqkv,
    const float* __restrict__ W0, ushort* __restrict__ xb,
    ushort* __restrict__ whT, ushort* __restrict__ w0T) {
  __shared__ float T[64][65];
  const int tid = threadIdx.x;
  int bid = blockIdx.x;

  if (bid < 1024) {  // ---- x -> bf16 ----
    const size_t i = ((size_t)bid * 256 + tid) * 4;
    const float4 v = *(const float4*)&X[i];
    ushort4 hv = {f2bf(v.x), f2bf(v.y), f2bf(v.z), f2bf(v.w)};
    *(ushort4*)&xb[i] = hv;
    return;
  }
  bid -= 1024;
  if (bid < 384) {  // ---- Wqkv [256][6144] -> whT [6144][256], permuted ----
    const int n0 = (bid % 96) * 64;
    const int k0 = (bid / 96) * 64;
    {
      const int row = tid >> 2;
      const int c0 = (tid & 3) * 16;
#pragma unroll
      for (int j = 0; j < 16; j += 4) {
        const float4 v = *(const float4*)&Wqkv[(size_t)(k0 + row) * 6144 + n0 + c0 + j];
        T[row][c0 + j + 0] = v.x; T[row][c0 + j + 1] = v.y;
        T[row][c0 + j + 2] = v.z; T[row][c0 + j + 3] = v.w;
      }
    }
    __syncthreads();
    {
      const int nn = tid >> 2;
      const int kk0 = (tid & 3) * 16;
      const int n = n0 + nn;
      const int seg = n >> 11, h = n & 7, d = (n & 2047) >> 3;
      const int p = seg * 2048 + h * 256 + d;
      ushort hv[16];
#pragma unroll
      for (int j = 0; j < 16; ++j) hv[j] = f2bf(T[kk0 + j][nn]);
      const size_t base = (size_t)p * 256 + k0 + kk0;
#pragma unroll
      for (int j = 0; j < 16; j += 8) *(v8s*)&whT[base + j] = *(v8s*)&hv[j];
    }
    return;
  }
  bid -= 384;
  {  // ---- W0 [2048][256] -> w0T [256][2048], k-permuted ----
    const int e0 = (bid & 3) * 64;
    const int k0 = (bid >> 2) * 64;
    {
      const int row = tid >> 2;
      const int c0 = (tid & 3) * 16;
#pragma unroll
      for (int j = 0; j < 16; j += 4) {
        const float4 v = *(const float4*)&W0[(size_t)(k0 + row) * 256 + e0 + c0 + j];
        T[row][c0 + j + 0] = v.x; T[row][c0 + j + 1] = v.y;
        T[row][c0 + j + 2] = v.z; T[row][c0 + j + 3] = v.w;
      }
    }
    __syncthreads();
    {
      const int ee = tid >> 2;
      const int kk0 = (tid & 3) * 16;
#pragma unroll
      for (int j = 0; j < 16; ++j) {
        const int k = k0 + kk0 + j;      // original row = d*8+h
        const int d = k >> 3, h = k & 7;
        w0T[(size_t)(e0 + ee) * 2048 + h * 256 + d] = f2bf(T[kk0 + j][ee]);
      }
    }
  }
}

// ---------------------------------------------------------------------------
// 256x256 tile, BK=64, 8 waves (512 thr), 8-phase pipelined GEMM body.
// K = 256 fixed (4 K-tiles, 2 fully-unrolled iterations).
// LDS A/B: [2 buf][256 rows][64 cols] bf16 (128B rows = 8 16B slots).
// Swizzle: physical slot = logical slot ^ (row&7)  (both sides).
// ---------------------------------------------------------------------------
template <int STRIDE>
__device__ __forceinline__ void gemm256_8ph(
    const ushort* __restrict__ gA, const ushort* __restrict__ gB,
    ushort (&AS)[2][16384], ushort (&BS)[2][16384],
    v4f (&acc)[2][2][4][2]) {
  const int tid = threadIdx.x;
  const int wave = tid >> 6, lane = tid & 63;
  const int wm = wave >> 2, wn = wave & 3;
  const int quad = lane >> 4, l15 = lane & 15;
  // stage-side lane mapping: LDS dest linear (wave base + lane*16B); the
  // global source column is inverse-swizzled so that LDS physical slot
  // (lane&7) of row (lane>>3) holds logical slot (lane&7)^(lane>>3).
  const int srow = lane >> 3;                     // row within 8-row group
  const int scol = (((lane & 7) ^ srow) << 3);    // logical col (ushort)

  auto stage = [&](int op, int buf, int half, int kt) {
#pragma unroll
    for (int j = 0; j < 2; ++j) {
      const size_t grow =
          (size_t)(half * 128 + j * 64 + wave * 8 + srow) * STRIDE + kt * 64 + scol;
      ushort* lb = op ? &BS[buf][half * 8192 + j * 4096 + wave * 512]
                      : &AS[buf][half * 8192 + j * 4096 + wave * 512];
      GLOAD_LDS16((op ? gB : gA) + grow, lb);
    }
  };

  // prologue: K0 all 4 half-tiles (8 loads), K1 A-half0 + B-half0 (4 loads)
  stage(0, 0, 0, 0); stage(0, 0, 1, 0); stage(1, 0, 0, 0); stage(1, 0, 1, 0);
  stage(0, 1, 0, 1); stage(1, 1, 0, 1);
  VMCNT4();   // K0 landed (K1's 4 loads may remain outstanding)
  SBAR();

#pragma unroll
  for (int it = 0; it < 2; ++it) {
    const int t0 = it * 2;
#pragma unroll
    for (int p = 0; p < 8; ++p) {
      const int kb = p >> 2;               // read buffer / relative K-tile
      const int qr = (p >> 1) & 1, qc = p & 1;
      v8s af[4][2], bfr[2][2];
#pragma unroll
      for (int ri = 0; ri < 4; ++ri) {
        const int r = qr * 128 + wm * 64 + ri * 16 + l15;
        const int rx = r & 7;              // = l15 & 7
#pragma unroll
        for (int ks = 0; ks < 2; ++ks)
          af[ri][ks] = *(const v8s*)&AS[kb][r * 64 + ((((ks << 2) | quad) ^ rx) << 3)];
      }
#pragma unroll
      for (int ci = 0; ci < 2; ++ci) {
        const int r = qc * 128 + wn * 32 + ci * 16 + l15;
        const int rx = r & 7;
#pragma unroll
        for (int ks = 0; ks < 2; ++ks)
          bfr[ci][ks] = *(const v8s*)&BS[kb][r * 64 + ((((ks << 2) | quad) ^ rx) << 3)];
      }
      {  // stage schedule: ph1..8 -> A1/B1(t0+1), A0/B0(t0+2), A1/B1(t0+2),
         //                 A0/B0(t0+3); staged half was last read ph<=p-1.
        const int st = t0 + 1 + ((p + 2) >> 2);
        if (st < 4) stage(p & 1, st & 1, 1 - ((p >> 1) & 1), st);
      }
      SBAR();
      __builtin_amdgcn_s_setprio(1);
#pragma unroll
      for (int ri = 0; ri < 4; ++ri)
#pragma unroll
        for (int ci = 0; ci < 2; ++ci)
#pragma unroll
          for (int ks = 0; ks < 2; ++ks)
            acc[qr][qc][ri][ci] = __builtin_amdgcn_mfma_f32_16x16x32_bf16(
                af[ri][ks], bfr[ci][ks], acc[qr][qc][ri][ci], 0, 0, 0);
      __builtin_amdgcn_s_setprio(0);
      if (p == 3 || p == 7) { if (it == 0) VMCNT4(); else VMCNT0(); }
      SBAR();
    }
  }
}

// ---------------------------------------------------------------------------
// Kernel A: qkv = x @ Wqkv + bqkv.  grid (24, 16), 512 thr, 256x256 tile.
// ---------------------------------------------------------------------------
__global__ __launch_bounds__(512, 2) void qkv8(
    const ushort* __restrict__ xb, const ushort* __restrict__ whT,
    const float* __restrict__ bias, ushort* __restrict__ qkvb) {
  __shared__ ushort AS[2][16384];
  __shared__ ushort BS[2][16384];
  const int tid = threadIdx.x;
  const int wave = tid >> 6, lane = tid & 63;
  const int wm = wave >> 2, wn = wave & 3;
  const int quad = lane >> 4, l15 = lane & 15;
  const int c0 = blockIdx.x * 256;
  const int r0 = blockIdx.y * 256;

  v4f acc[2][2][4][2] = {};
  gemm256_8ph<256>(xb + (size_t)r0 * 256, whT + (size_t)c0 * 256, AS, BS, acc);

#pragma unroll
  for (int qc2 = 0; qc2 < 2; ++qc2)
#pragma unroll
    for (int ci = 0; ci < 2; ++ci) {
      const int cc = c0 + qc2 * 128 + wn * 32 + ci * 16 + l15;
      const int cseg = cc >> 11;
      const int hh = (cc & 2047) >> 8;
      const int d = cc & 255;
      const float bv = bias[cseg * 2048 + d * 8 + hh];
#pragma unroll
      for (int qr = 0; qr < 2; ++qr)
#pragma unroll
        for (int ri = 0; ri < 4; ++ri)
#pragma unroll
          for (int rg = 0; rg < 4; ++rg) {
            const int r = r0 + qr * 128 + wm * 64 + ri * 16 + quad * 4 + rg;
            const int g = r * 3 + cseg;
            const int seg = g >> 12;       // q/k/v
            const int tok = g & 4095;      // = b*1024 + n
            float val = acc[qr][qc2][ri][ci][rg] + bv;
            if (seg == 0) val *= 0.0625f;  // pre-scale q by D^-0.5
            qkvb[(size_t)seg * SEGSZ + (size_t)tok * 2048 + hh * 256 + d] = f2bf(val);
          }
    }
}

// ---------------------------------------------------------------------------
// Kernel B (fused): blocks 0..511 = score stats (256x256 tiles, col-sums of
// exp + diagonal); blocks 512..639 = y_h = v_h @ W0_h partials (no dg).
// Scores ids keep id%8 == bh%8 (XCD L2 swizzle); y blocks fill the tail.
// ---------------------------------------------------------------------------
__global__ __launch_bounds__(512, 2) void mid8(
    const ushort* __restrict__ qkvb, const ushort* __restrict__ w0T,
    float* __restrict__ pl, float* __restrict__ sd_ws,
    ushort* __restrict__ partial) {
  __shared__ ushort AS[2][16384];
  __shared__ ushort BS[2][16384];
  __shared__ float redL[2][4][64];
  const int tid = threadIdx.x;
  const int wave = tid >> 6, lane = tid & 63;
  const int wm = wave >> 2, wn = wave & 3;
  const int quad = lane >> 4, l15 = lane & 15;
  const int id = blockIdx.x;

  v4f acc[2][2][4][2] = {};

  if (id < 512) {
    // ---------------- scores branch ----------------
    const int c = id & 7, inner = id >> 3;
    const int bh = (inner >> 4) * 8 + c;
    const int tile = inner & 15;
    const int tt0 = (tile >> 2) * 256;     // key-column tile
    const int nn0 = (tile & 3) * 256;      // query-row tile (inner: L2 reuse)
    const int b = bh >> 3, h = bh & 7;
    const ushort* Qg = qkvb + (size_t)b * 2097152 + h * 256 + (size_t)nn0 * 2048;
    const ushort* Kg = qkvb + SEGSZ + (size_t)b * 2097152 + h * 256 + (size_t)tt0 * 2048;
    gemm256_8ph<2048>(Qg, Kg, AS, BS, acc);

    // ---- column sums of exp(s): C col = key t, rows = queries n ----
    float lsum[2][2];
#pragma unroll
    for (int qc2 = 0; qc2 < 2; ++qc2)
#pragma unroll
      for (int ci = 0; ci < 2; ++ci) {
        float s = 0.f;
#pragma unroll
        for (int qr = 0; qr < 2; ++qr)
#pragma unroll
          for (int ri = 0; ri < 4; ++ri)
#pragma unroll
            for (int rg = 0; rg < 4; ++rg)
              s += __expf(acc[qr][qc2][ri][ci][rg]);
        s += __shfl_xor(s, 16, 64);
        s += __shfl_xor(s, 32, 64);
        lsum[qc2][ci] = s;                 // sum over this wave's 128 rows
      }
    if (quad == 0) {
#pragma unroll
      for (int qc2 = 0; qc2 < 2; ++qc2)
#pragma unroll
        for (int ci = 0; ci < 2; ++ci)
          redL[wm][wn][(qc2 * 2 + ci) * 16 + l15] = lsum[qc2][ci];
    }
    __syncthreads();
    if (wm == 0 && quad == 0) {
#pragma unroll
      for (int qc2 = 0; qc2 < 2; ++qc2)
#pragma unroll
        for (int ci = 0; ci < 2; ++ci) {
          const int t = tt0 + qc2 * 128 + wn * 32 + ci * 16 + l15;
          const float l = lsum[qc2][ci] + redL[1][wn][(qc2 * 2 + ci) * 16 + l15];
          pl[((size_t)bh * 1024 + t) * 4 + (nn0 >> 8)] = l;
        }
    }

    // ---- diagonal capture (tt0 == nn0 tiles) ----
    if (tt0 == nn0) {
#pragma unroll
      for (int qr = 0; qr < 2; ++qr)
#pragma unroll
        for (int ci = 0; ci < 2; ++ci)
#pragma unroll
          for (int ri = 0; ri < 4; ++ri)
#pragma unroll
            for (int rg = 0; rg < 4; ++rg)
              if (wn * 2 + ci - wm * 4 == ri && (l15 >> 2) == quad &&
                  (l15 & 3) == rg) {
                const int t = tt0 + qr * 128 + wm * 64 + ri * 16 + l15;
                sd_ws[(size_t)bh * 1024 + t] = acc[qr][qr][ri][ci][rg];
              }
    }
  } else {
    // ---------------- y = v_h @ W0_h branch (no dg) ----------------
    const int j = id - 512;
    const int h = j >> 4;
    const int tok0 = (j & 15) * 256;
    const ushort* Ag = qkvb + 2 * (size_t)SEGSZ + (size_t)tok0 * 2048 + h * 256;
    const ushort* Bg = w0T + h * 256;      // rows e = 0..255, stride 2048
    gemm256_8ph<2048>(Ag, Bg, AS, BS, acc);

#pragma unroll
    for (int qr = 0; qr < 2; ++qr)
#pragma unroll
      for (int ri = 0; ri < 4; ++ri)
#pragma unroll
        for (int rg = 0; rg < 4; ++rg) {
          const int tok = tok0 + qr * 128 + wm * 64 + ri * 16 + quad * 4 + rg;
#pragma unroll
          for (int qc2 = 0; qc2 < 2; ++qc2)
#pragma unroll
            for (int ci = 0; ci < 2; ++ci) {
              const int e = qc2 * 128 + wn * 32 + ci * 16 + l15;
              partial[(size_t)h * 1048576 + (size_t)tok * 256 + e] =
                  f2bf(acc[qr][qc2][ri][ci][rg]);
            }
        }
  }
}

// ---------------------------------------------------------------------------
// Fallback kernels (workspace too small for partials): atomic av with
// in-kernel diag (128x128 legacy tile).  Not used on the benched path.
// ---------------------------------------------------------------------------
__global__ __launch_bounds__(256) void av_atomic(
    const ushort* __restrict__ vb, const ushort* __restrict__ w0T,
    const float* __restrict__ pl, const float* __restrict__ sd,
    float* __restrict__ out) {
  __shared__ ushort As[128 * 32];
  __shared__ ushort Bs[128 * 32];
  __shared__ float diagS[128];
  const int tid = threadIdx.x;
  const int wave = tid >> 6, lane = tid & 63;
  const int quad = lane >> 4, l15 = lane & 15;
  const int e0 = blockIdx.x * 128;
  const int tok0 = blockIdx.y * 128;
  const int h = blockIdx.z;
  const int kbase = h * 256;
  const int wr = (wave >> 1) * 64;
  const int wc = (wave & 1) * 64;

  if (tid < 128) {
    const int bh = (tok0 >> 10) * 8 + h;
    const int t = (tok0 & 1023) + tid;
    const size_t base = ((size_t)bh * 1024 + t) * 4;
    float l = 0.f;
#pragma unroll
    for (int cc = 0; cc < 4; ++cc) l += pl[base + cc];
    diagS[tid] = __expf(sd[(size_t)bh * 1024 + t]) / l;
  }

  v4f acc[4][4] = {};

  for (int d0 = 0; d0 < 256; d0 += 32) {
#pragma unroll
    for (int half = 0; half < 2; ++half) {
      const int rr = wave * 32 + half * 16;
      const int row = rr + (lane >> 2);
      const int gcol = kbase + d0 + (lane & 3) * 8;
      GLOAD_LDS16(vb + (size_t)(tok0 + row) * 2048 + gcol, &As[rr * 32]);
      GLOAD_LDS16(w0T + (size_t)(e0 + row) * 2048 + gcol, &Bs[rr * 32]);
    }
    __syncthreads();

    v8s aF[4], bF[4];
#pragma unroll
    for (int i = 0; i < 4; ++i) {
      aF[i] = *(const v8s*)&As[(wr + i * 16 + l15) * 32 + quad * 8];
      bF[i] = *(const v8s*)&Bs[(wc + i * 16 + l15) * 32 + quad * 8];
    }
#pragma unroll
    for (int ri = 0; ri < 4; ++ri)
#pragma unroll
      for (int ci = 0; ci < 4; ++ci)
        acc[ri][ci] =
            __builtin_amdgcn_mfma_f32_16x16x32_bf16(aF[ri], bF[ci], acc[ri][ci], 0, 0, 0);
    __syncthreads();
  }

#pragma unroll
  for (int ri = 0; ri < 4; ++ri)
#pragma unroll
    for (int rg = 0; rg < 4; ++rg) {
      const int lrow = wr + ri * 16 + quad * 4 + rg;
      const int tok = tok0 + lrow;
      const float dg = diagS[lrow];
#pragma unroll
      for (int ci = 0; ci < 4; ++ci) {
        const int e = e0 + wc + ci * 16 + l15;
        atomicAdd(&out[(size_t)tok * 256 + e], acc[ri][ci][rg] * dg);
      }
    }
}

__global__ void init_out(const float* __restrict__ b0, float* __restrict__ out) {
  const int i = blockIdx.x * 256 + threadIdx.x;
  const int e0 = (i & 63) << 2;
  *(float4*)&out[(size_t)i * 4] = *(const float4*)&b0[e0];
}

// ---------------------------------------------------------------------------
// reduce_out: out[tok][e] = b0[e] + sum_h dg_h(tok) * y_h[tok][e].
// dg computed per-block in LDS: block covers 4 tokens (256 float4-groups).
// ---------------------------------------------------------------------------
__global__ void reduce_out(const ushort* __restrict__ partial,
                           const float* __restrict__ pl,
                           const float* __restrict__ sd,
                           const float* __restrict__ b0, float* __restrict__ out) {
  __shared__ float dgS[32];
  const int i = blockIdx.x * 256 + threadIdx.x;  // 262144 float4 groups
  const int tbase = blockIdx.x * 4;              // 4 tokens per block
  if (threadIdx.x < 32) {
    const int tl = threadIdx.x >> 3, h = threadIdx.x & 7;
    const int tok = tbase + tl;
    const int bh = (tok >> 10) * 8 + h;
    const int t = tok & 1023;
    const size_t base = ((size_t)bh * 1024 + t) * 4;
    float l = 0.f;
#pragma unroll
    for (int cc = 0; cc < 4; ++cc) l += pl[base + cc];
    dgS[threadIdx.x] = __expf(sd[(size_t)bh * 1024 + t]) / l;
  }
  __syncthreads();
  const int tl = threadIdx.x >> 6;
  const int e0 = (i & 63) << 2;
  float4 a = *(const float4*)&b0[e0];
#pragma unroll
  for (int h = 0; h < 8; ++h) {
    const float dg = dgS[tl * 8 + h];
    const ushort4 p = *(const ushort4*)&partial[(size_t)h * 1048576 + (size_t)i * 4];
    a.x += dg * bf2f(p.x); a.y += dg * bf2f(p.y);
    a.z += dg * bf2f(p.z); a.w += dg * bf2f(p.w);
  }
  *(float4*)&out[(size_t)i * 4] = a;
}

extern "C" void kernel_launch(void* const* d_in, const int* in_sizes, int n_in,
                              void* d_out, int out_size, void* d_ws, size_t ws_size,
                              hipStream_t stream) {
  const float* x    = (const float*)d_in[0];
  const float* Wqkv = (const float*)d_in[1];
  const float* bqkv = (const float*)d_in[2];
  const float* W0   = (const float*)d_in[3];
  const float* b0   = (const float*)d_in[4];
  float* out = (float*)d_out;

  float*  pl   = (float*)d_ws;                     // 262144 f (131072 used)
  float*  sd   = pl + 262144;                      // 32768 f
  ushort* qkvb = (ushort*)(sd + 32768);            // 3*SEGSZ us (q|k|v)
  ushort* xb   = qkvb + 3 * (size_t)SEGSZ;         // 1048576 us
  ushort* whT  = xb + 1048576;                     // 1572864 us
  ushort* w0T  = whT + 1572864;                    // 524288 us
  ushort* partial = w0T + 524288;                  // 8*1048576 us (optional)

  ushort* vb = qkvb + 2 * (size_t)SEGSZ;

  const size_t need_base =
      (size_t)(262144 + 32768) * 4 + (size_t)SEGSZ * 3 * 2 +
      (size_t)(1048576 + 1572864 + 524288) * 2;
  const bool full = ws_size >= need_base + (size_t)8 * 1048576 * 2;

  prep<<<1536, 256, 0, stream>>>(x, Wqkv, W0, xb, whT, w0T);
  qkv8<<<dim3(24, 16), 512, 0, stream>>>(xb, whT, bqkv, qkvb);
  if (full) {
    mid8<<<640, 512, 0, stream>>>(qkvb, w0T, pl, sd, partial);
    reduce_out<<<1024, 256, 0, stream>>>(partial, pl, sd, b0, out);
  } else {
    mid8<<<512, 512, 0, stream>>>(qkvb, w0T, pl, sd, nullptr);
    init_out<<<1024, 256, 0, stream>>>(b0, out);
    av_atomic<<<dim3(2, 32, 8), 256, 0, stream>>>(vb, w0T, pl, sd, out);
  }
}